// Round 3
// baseline (271.025 us; speedup 1.0000x reference)
//
#include <hip/hip_runtime.h>
#include <math.h>

#define N_CAT   1024
#define IN_DIM  4096
#define HID     4096
#define OUT_DIM 50257
#define XDIM    (N_CAT + IN_DIM)   // 5120 (GRU input width)
#define OCDIM   (N_CAT + HID)      // 5120 (output-proj input width)
#define NB_OUT  ((OUT_DIM + 3) / 4)  // 12565 blocks in out_gemv
#define NROW_G  (3 * HID)            // 12288 gate rows per matrix

// ws layout (floats):
//   [0, 50304)        logits (padded)
//   [50304, 54400)    h_new aligned copy
//   [54400, 67008)    per-block max partials (12565, padded)
//   [67008, 79616)    per-block sumexp partials
//   [79616, 91904)    gi = w_ih @ x + b_ih   (12288)
//   [91904, 104192)   gh = w_hh @ h + b_hh   (12288)
#define WS_LOGITS 0
#define WS_HNEW   50304
#define WS_PMAX   54400
#define WS_PSUM   67008
#define WS_GI     79616
#define WS_GH     91904

__device__ __forceinline__ float dot4(float4 a, float4 b) {
    return a.x * b.x + a.y * b.y + a.z * b.z + a.w * b.w;
}

__device__ __forceinline__ float wave_reduce_sum(float v) {
    #pragma unroll
    for (int off = 32; off > 0; off >>= 1)
        v += __shfl_down(v, off, 64);
    return v;
}

// ---------------- Kernel 1: gate GEMVs, wave-per-row -----------------------
// grid = 6144 blocks x 256 threads (4 waves).
// Blocks [0, 3072): rows of w_ih (width 5120) vs x = [cat | inp] -> gi
// Blocks [3072, 6144): rows of w_hh (width 4096) vs hid         -> gh
// Each block streams 4 consecutive rows = 64-80 KB contiguous.
__global__ __launch_bounds__(256) void gates_gemv(
    const float* __restrict__ cat,
    const float* __restrict__ inp,
    const float* __restrict__ hid,
    const float* __restrict__ w_ih,
    const float* __restrict__ b_ih,
    const float* __restrict__ w_hh,
    const float* __restrict__ b_hh,
    float* __restrict__ gi,
    float* __restrict__ gh)
{
    const int lane = threadIdx.x & 63;
    const int wave = threadIdx.x >> 6;

    if (blockIdx.x < 3072) {
        const int row = blockIdx.x * 4 + wave;          // < 12288
        const float4* cat4 = (const float4*)cat;        // 256 f4
        const float4* in4  = (const float4*)inp;        // 1024 f4
        const float4* wrow = (const float4*)w_ih + (size_t)row * (XDIM / 4);
        float acc = 0.f;
        #pragma unroll
        for (int k = 0; k < 4; ++k) {
            const int idx = lane + k * 64;
            acc += dot4(wrow[idx], cat4[idx]);
        }
        #pragma unroll
        for (int k = 0; k < 16; ++k) {
            const int idx = lane + k * 64;
            acc += dot4(wrow[256 + idx], in4[idx]);
        }
        acc = wave_reduce_sum(acc);
        if (lane == 0) gi[row] = acc + b_ih[row];
    } else {
        const int row = (blockIdx.x - 3072) * 4 + wave; // < 12288
        const float4* h4   = (const float4*)hid;        // 1024 f4
        const float4* wrow = (const float4*)w_hh + (size_t)row * (HID / 4);
        float acc = 0.f;
        #pragma unroll
        for (int k = 0; k < 16; ++k) {
            const int idx = lane + k * 64;
            acc += dot4(wrow[idx], h4[idx]);
        }
        acc = wave_reduce_sum(acc);
        if (lane == 0) gh[row] = acc + b_hh[row];
    }
}

// ---------------- Kernel 2: GRU elementwise combine -> h_new ---------------
// grid = 16 blocks x 256 threads = 4096.
__global__ __launch_bounds__(256) void gru_combine(
    const float* __restrict__ gi,
    const float* __restrict__ gh,
    const float* __restrict__ hid,
    float* __restrict__ hnew_out,   // d_out + OUT_DIM
    float* __restrict__ hnew_ws)
{
    const int j = blockIdx.x * 256 + threadIdx.x;  // < 4096
    const float gi_r = gi[j];
    const float gi_z = gi[j + HID];
    const float gi_n = gi[j + 2 * HID];
    const float gh_r = gh[j];
    const float gh_z = gh[j + HID];
    const float gh_n = gh[j + 2 * HID];

    const float r = 1.f / (1.f + expf(-(gi_r + gh_r)));
    const float z = 1.f / (1.f + expf(-(gi_z + gh_z)));
    const float n = tanhf(gi_n + r * gh_n);
    const float hn = (1.f - z) * n + z * hid[j];
    hnew_out[j] = hn;
    hnew_ws[j]  = hn;
}

// ---------------- Kernel 3: output projection + per-block softmax partials -
// grid = NB_OUT blocks of 256 (4 waves); wave w does row 4*b+w.
__global__ __launch_bounds__(256) void out_gemv(
    const float* __restrict__ cat,
    const float* __restrict__ hnew,
    const float* __restrict__ w_out,
    const float* __restrict__ b_out,
    float* __restrict__ logits,
    float* __restrict__ pmax,
    float* __restrict__ psum)
{
    const int lane  = threadIdx.x & 63;
    const int wave  = threadIdx.x >> 6;
    const int row   = blockIdx.x * 4 + wave;
    const bool valid = (row < OUT_DIM);

    float acc = 0.f;
    if (valid) {
        const float4* cat4 = (const float4*)cat;                      // 256 f4
        const float4* h4   = (const float4*)hnew;                     // 1024 f4
        const float4* wrow = (const float4*)w_out + (size_t)row * (OCDIM / 4);
        #pragma unroll
        for (int k = 0; k < 4; ++k) {
            const int idx = lane + k * 64;
            acc += dot4(wrow[idx], cat4[idx]);
        }
        #pragma unroll
        for (int k = 0; k < 16; ++k) {
            const int idx = lane + k * 64;
            acc += dot4(wrow[256 + idx], h4[idx]);
        }
    }
    acc = wave_reduce_sum(acc);

    __shared__ float svals[4];
    if (lane == 0)
        svals[wave] = valid ? (acc + b_out[row]) : -INFINITY;
    __syncthreads();

    if (threadIdx.x == 0) {
        const float v0 = svals[0], v1 = svals[1], v2 = svals[2], v3 = svals[3];
        const float m = fmaxf(fmaxf(v0, v1), fmaxf(v2, v3));
        const float s = expf(v0 - m) + expf(v1 - m) + expf(v2 - m) + expf(v3 - m);
        pmax[blockIdx.x] = m;
        psum[blockIdx.x] = s;
    }
    if (lane == 0 && valid)
        logits[row] = svals[wave];
}

// ---------------- Kernel 4: logZ (redundant per block) + write logp --------
// grid = 50 blocks x 256. Each block combines all partials (L2-resident,
// ~100 KB) then writes its slice of logp.
__global__ __launch_bounds__(256) void softmax_write(
    const float* __restrict__ pmax,
    const float* __restrict__ psum,
    const float* __restrict__ logits,
    float* __restrict__ out)
{
    __shared__ float sred[4];
    __shared__ float sb;
    const int tid  = threadIdx.x;
    const int lane = tid & 63;
    const int wave = tid >> 6;

    float m = -INFINITY;
    #pragma unroll 8
    for (int i = tid; i < NB_OUT; i += 256)
        m = fmaxf(m, pmax[i]);
    #pragma unroll
    for (int off = 32; off > 0; off >>= 1)
        m = fmaxf(m, __shfl_down(m, off, 64));
    if (lane == 0) sred[wave] = m;
    __syncthreads();
    const float M = fmaxf(fmaxf(sred[0], sred[1]), fmaxf(sred[2], sred[3]));
    __syncthreads();

    float s = 0.f;
    #pragma unroll 8
    for (int i = tid; i < NB_OUT; i += 256)
        s += psum[i] * expf(pmax[i] - M);
    s = wave_reduce_sum(s);
    if (lane == 0) sred[wave] = s;
    __syncthreads();
    if (tid == 0)
        sb = M + logf(sred[0] + sred[1] + sred[2] + sred[3]);
    __syncthreads();
    const float logZ = sb;

    const int n4 = OUT_DIM / 4;   // 12564
    for (int t = blockIdx.x * 256 + tid; t < n4; t += 50 * 256) {
        float4 v = ((const float4*)logits)[t];
        v.x -= logZ; v.y -= logZ; v.z -= logZ; v.w -= logZ;
        ((float4*)out)[t] = v;
    }
    if (blockIdx.x == 0 && tid == 0)
        out[OUT_DIM - 1] = logits[OUT_DIM - 1] - logZ;
}

extern "C" void kernel_launch(void* const* d_in, const int* in_sizes, int n_in,
                              void* d_out, int out_size, void* d_ws, size_t ws_size,
                              hipStream_t stream) {
    (void)in_sizes; (void)n_in; (void)out_size; (void)ws_size;

    const float* cat   = (const float*)d_in[0];
    const float* inp   = (const float*)d_in[1];
    const float* hid   = (const float*)d_in[2];
    const float* w_ih  = (const float*)d_in[3];
    const float* b_ih  = (const float*)d_in[4];
    const float* w_hh  = (const float*)d_in[5];
    const float* b_hh  = (const float*)d_in[6];
    const float* w_out = (const float*)d_in[7];
    const float* b_out = (const float*)d_in[8];

    float* out    = (float*)d_out;          // [0,50257) logp, [50257,54353) h_new
    float* ws_f   = (float*)d_ws;
    float* logits = ws_f + WS_LOGITS;
    float* hnew   = ws_f + WS_HNEW;
    float* pmax   = ws_f + WS_PMAX;
    float* psum   = ws_f + WS_PSUM;
    float* gi     = ws_f + WS_GI;
    float* gh     = ws_f + WS_GH;

    // K1: gi = w_ih @ [cat|inp] + b_ih ; gh = w_hh @ hid + b_hh
    gates_gemv<<<6144, 256, 0, stream>>>(cat, inp, hid, w_ih, b_ih, w_hh, b_hh,
                                         gi, gh);
    // K2: h_new from gates
    gru_combine<<<16, 256, 0, stream>>>(gi, gh, hid, out + OUT_DIM, hnew);
    // K3: logits = [cat, h_new] @ w_out^T + b_out, plus per-block (max,sumexp)
    out_gemv<<<NB_OUT, 256, 0, stream>>>(cat, hnew, w_out, b_out,
                                         logits, pmax, psum);
    // K4: logZ + logp write
    softmax_write<<<50, 256, 0, stream>>>(pmax, psum, logits, out);
}

// Round 4
// 241.155 us; speedup vs baseline: 1.1239x; 1.1239x over previous
//
#include <hip/hip_runtime.h>
#include <math.h>

#define N_CAT   1024
#define IN_DIM  4096
#define HID     4096
#define OUT_DIM 50257
#define XDIM    (N_CAT + IN_DIM)   // 5120 (GRU input width)
#define OCDIM   (N_CAT + HID)      // 5120 (output-proj input width)
#define NB_OUT  ((OUT_DIM + 3) / 4)  // 12565 blocks in out_gemv

// ws layout (floats):
//   [0, 50304)        logits (padded)
//   [50304, 54400)    h_new aligned copy
//   [54400, 67008)    per-block max partials (12565, padded)
//   [67008, 79616)    per-block sumexp partials
#define WS_LOGITS 0
#define WS_HNEW   50304
#define WS_PMAX   54400
#define WS_PSUM   67008

// native vector type so __builtin_nontemporal_load works
typedef float f4 __attribute__((ext_vector_type(4)));

__device__ __forceinline__ float dot4(f4 a, f4 b) {
    return a.x * b.x + a.y * b.y + a.z * b.z + a.w * b.w;
}

// non-temporal (evict-first) load for stream-once weight data
__device__ __forceinline__ f4 ldnt(const f4* p) {
    return __builtin_nontemporal_load(p);
}

__device__ __forceinline__ float wave_reduce_sum(float v) {
    #pragma unroll
    for (int off = 32; off > 0; off >>= 1)
        v += __shfl_down(v, off, 64);
    return v;
}

// ---------------- Kernel A: GRU cell via 6 fused GEMV rows per block -------
// grid = HID blocks, 256 threads. Block j computes h_new[j].
// (Round-2 proven structure; weight loads now non-temporal.)
__global__ __launch_bounds__(256) void gru_gemv(
    const float* __restrict__ cat,
    const float* __restrict__ inp,
    const float* __restrict__ hid,
    const float* __restrict__ w_ih,
    const float* __restrict__ b_ih,
    const float* __restrict__ w_hh,
    const float* __restrict__ b_hh,
    float* __restrict__ hnew_out,    // d_out + OUT_DIM (final output slot)
    float* __restrict__ hnew_ws)     // aligned ws copy for kernel B
{
    const int j    = blockIdx.x;
    const int tid  = threadIdx.x;
    const int lane = tid & 63;
    const int wave = tid >> 6;

    const f4* cat4 = (const f4*)cat;   // 256 f4
    const f4* in4  = (const f4*)inp;   // 1024 f4
    const f4* h4   = (const f4*)hid;   // 1024 f4
    const f4* wi4  = (const f4*)w_ih;
    const f4* wh4  = (const f4*)w_hh;

    float si[3] = {0.f, 0.f, 0.f};
    float sh[3] = {0.f, 0.f, 0.f};

    #pragma unroll
    for (int g = 0; g < 3; ++g) {
        const size_t row = (size_t)j + (size_t)g * HID;
        const f4* wrow = wi4 + row * (XDIM / 4);
        // category segment: 256 f4 -> exactly one per thread
        si[g] += dot4(ldnt(wrow + tid), cat4[tid]);
        // input segment: 1024 f4
        #pragma unroll
        for (int k = 0; k < 4; ++k) {
            const int idx = tid + k * 256;
            si[g] += dot4(ldnt(wrow + 256 + idx), in4[idx]);
        }
        const f4* hrow = wh4 + row * (HID / 4);
        #pragma unroll
        for (int k = 0; k < 4; ++k) {
            const int idx = tid + k * 256;
            sh[g] += dot4(ldnt(hrow + idx), h4[idx]);
        }
    }

    __shared__ float red[4][6];
    float vals[6] = {si[0], si[1], si[2], sh[0], sh[1], sh[2]};
    #pragma unroll
    for (int q = 0; q < 6; ++q) {
        const float r = wave_reduce_sum(vals[q]);
        if (lane == 0) red[wave][q] = r;
    }
    __syncthreads();

    if (tid == 0) {
        float t[6];
        #pragma unroll
        for (int q = 0; q < 6; ++q)
            t[q] = red[0][q] + red[1][q] + red[2][q] + red[3][q];
        const float gi_r = t[0] + b_ih[j];
        const float gi_z = t[1] + b_ih[j + HID];
        const float gi_n = t[2] + b_ih[j + 2 * HID];
        const float gh_r = t[3] + b_hh[j];
        const float gh_z = t[4] + b_hh[j + HID];
        const float gh_n = t[5] + b_hh[j + 2 * HID];

        const float r = 1.f / (1.f + expf(-(gi_r + gh_r)));
        const float z = 1.f / (1.f + expf(-(gi_z + gh_z)));
        const float n = tanhf(gi_n + r * gh_n);
        const float hn = (1.f - z) * n + z * hid[j];
        hnew_out[j] = hn;
        hnew_ws[j]  = hn;
    }
}

// ---------------- Kernel B: output projection + per-block softmax partials -
// grid = NB_OUT blocks of 256 (4 waves); wave w does row 4*b+w.
__global__ __launch_bounds__(256) void out_gemv(
    const float* __restrict__ cat,
    const float* __restrict__ hnew,
    const float* __restrict__ w_out,
    const float* __restrict__ b_out,
    float* __restrict__ logits,
    float* __restrict__ pmax,
    float* __restrict__ psum)
{
    const int lane  = threadIdx.x & 63;
    const int wave  = threadIdx.x >> 6;
    const int row   = blockIdx.x * 4 + wave;
    const bool valid = (row < OUT_DIM);

    float acc = 0.f;
    if (valid) {
        const f4* cat4 = (const f4*)cat;                      // 256 f4
        const f4* h4   = (const f4*)hnew;                     // 1024 f4
        const f4* wrow = (const f4*)w_out + (size_t)row * (OCDIM / 4);
        #pragma unroll
        for (int k = 0; k < 4; ++k) {
            const int idx = lane + k * 64;
            acc += dot4(ldnt(wrow + idx), cat4[idx]);
        }
        #pragma unroll
        for (int k = 0; k < 16; ++k) {
            const int idx = lane + k * 64;
            acc += dot4(ldnt(wrow + 256 + idx), h4[idx]);
        }
    }
    acc = wave_reduce_sum(acc);

    __shared__ float svals[4];
    if (lane == 0)
        svals[wave] = valid ? (acc + b_out[row]) : -INFINITY;
    __syncthreads();

    if (threadIdx.x == 0) {
        const float v0 = svals[0], v1 = svals[1], v2 = svals[2], v3 = svals[3];
        const float m = fmaxf(fmaxf(v0, v1), fmaxf(v2, v3));
        const float s = expf(v0 - m) + expf(v1 - m) + expf(v2 - m) + expf(v3 - m);
        pmax[blockIdx.x] = m;
        psum[blockIdx.x] = s;
    }
    if (lane == 0 && valid)
        logits[row] = svals[wave];
}

// ---------------- Kernel C: logZ (redundant per block) + write logp --------
// grid = 50 blocks x 256. Each block combines all partials (L2/L3-resident,
// ~100 KB) then writes its slice of logp.
__global__ __launch_bounds__(256) void softmax_write(
    const float* __restrict__ pmax,
    const float* __restrict__ psum,
    const float* __restrict__ logits,
    float* __restrict__ out)
{
    __shared__ float sred[4];
    __shared__ float sb;
    const int tid  = threadIdx.x;
    const int lane = tid & 63;
    const int wave = tid >> 6;

    float m = -INFINITY;
    #pragma unroll 8
    for (int i = tid; i < NB_OUT; i += 256)
        m = fmaxf(m, pmax[i]);
    #pragma unroll
    for (int off = 32; off > 0; off >>= 1)
        m = fmaxf(m, __shfl_down(m, off, 64));
    if (lane == 0) sred[wave] = m;
    __syncthreads();
    const float M = fmaxf(fmaxf(sred[0], sred[1]), fmaxf(sred[2], sred[3]));
    __syncthreads();

    float s = 0.f;
    #pragma unroll 8
    for (int i = tid; i < NB_OUT; i += 256)
        s += psum[i] * expf(pmax[i] - M);
    s = wave_reduce_sum(s);
    if (lane == 0) sred[wave] = s;
    __syncthreads();
    if (tid == 0)
        sb = M + logf(sred[0] + sred[1] + sred[2] + sred[3]);
    __syncthreads();
    const float logZ = sb;

    const int n4 = OUT_DIM / 4;   // 12564
    for (int t = blockIdx.x * 256 + tid; t < n4; t += 50 * 256) {
        f4 v = ((const f4*)logits)[t];
        v.x -= logZ; v.y -= logZ; v.z -= logZ; v.w -= logZ;
        ((f4*)out)[t] = v;
    }
    if (blockIdx.x == 0 && tid == 0)
        out[OUT_DIM - 1] = logits[OUT_DIM - 1] - logZ;
}

extern "C" void kernel_launch(void* const* d_in, const int* in_sizes, int n_in,
                              void* d_out, int out_size, void* d_ws, size_t ws_size,
                              hipStream_t stream) {
    (void)in_sizes; (void)n_in; (void)out_size; (void)ws_size;

    const float* cat   = (const float*)d_in[0];
    const float* inp   = (const float*)d_in[1];
    const float* hid   = (const float*)d_in[2];
    const float* w_ih  = (const float*)d_in[3];
    const float* b_ih  = (const float*)d_in[4];
    const float* w_hh  = (const float*)d_in[5];
    const float* b_hh  = (const float*)d_in[6];
    const float* w_out = (const float*)d_in[7];
    const float* b_out = (const float*)d_in[8];

    float* out    = (float*)d_out;          // [0,50257) logp, [50257,54353) h_new
    float* ws_f   = (float*)d_ws;
    float* logits = ws_f + WS_LOGITS;
    float* hnew   = ws_f + WS_HNEW;
    float* pmax   = ws_f + WS_PMAX;
    float* psum   = ws_f + WS_PSUM;

    // A: GRU cell -> h_new
    gru_gemv<<<HID, 256, 0, stream>>>(cat, inp, hid, w_ih, b_ih, w_hh, b_hh,
                                      out + OUT_DIM, hnew);
    // B: logits = [cat, h_new] @ w_out^T + b_out, plus per-block (max,sumexp)
    out_gemv<<<NB_OUT, 256, 0, stream>>>(cat, hnew, w_out, b_out,
                                         logits, pmax, psum);
    // C: logZ + logp write
    softmax_write<<<50, 256, 0, stream>>>(pmax, psum, logits, out);
}